// Round 1
// baseline (438.138 us; speedup 1.0000x reference)
//
#include <hip/hip_runtime.h>
#include <math.h>

#define B_ 2
#define H_ 16
#define S_ 2048
#define CTX_ 1024
#define VD_ 288
#define VD2_ 576
#define FFN_ 512
#define FFNH_ 256
#define NH1_ 17
#define EPSILON_ 0.066f
#define LN_EPS_ 1e-5f
#define TPB_ 8                    // tokens per block
#define NBLK_ (B_ * S_ / TPB_)    // 512 blocks

__device__ __forceinline__ float gelu_exact(float x) {
    return 0.5f * x * (1.0f + erff(x * 0.70710678118654752440f));
}

// acc[j] += w * tokvec[j], tokvec given as two float4 (8 tokens)
__device__ __forceinline__ void fma8(float* a, float w, const float4& lo, const float4& hi) {
    a[0] += w * lo.x; a[1] += w * lo.y; a[2] += w * lo.z; a[3] += w * lo.w;
    a[4] += w * hi.x; a[5] += w * hi.y; a[6] += w * hi.z; a[7] += w * hi.w;
}

__device__ __forceinline__ void store8_gelu(float* dst, const float* a, float b) {
    float4 o0 = make_float4(gelu_exact(a[0] + b), gelu_exact(a[1] + b),
                            gelu_exact(a[2] + b), gelu_exact(a[3] + b));
    float4 o1 = make_float4(gelu_exact(a[4] + b), gelu_exact(a[5] + b),
                            gelu_exact(a[6] + b), gelu_exact(a[7] + b));
    *(float4*)&dst[0] = o0;
    *(float4*)&dst[4] = o1;
}

__global__ void zero_counts_kernel(int* __restrict__ counts) {
    int i = blockIdx.x * blockDim.x + threadIdx.x;
    if (i < CTX_) counts[i] = 0;
}

__global__ void count_tokens_kernel(const int* __restrict__ ids, int* __restrict__ counts) {
    int i = blockIdx.x * blockDim.x + threadIdx.x;
    if (i < B_ * S_) atomicAdd(&counts[ids[i]], 1);
}

__global__ __launch_bounds__(256) void token_mlp_kernel(
    const int* __restrict__ ids, const int* __restrict__ counts,
    const float* __restrict__ embW,
    const float* __restrict__ lnvw, const float* __restrict__ lnvb,
    const float* __restrict__ pW1, const float* __restrict__ pb1,
    const float* __restrict__ pW2, const float* __restrict__ pb2,
    const float* __restrict__ lncw, const float* __restrict__ lncb,
    const float* __restrict__ fW1, const float* __restrict__ fb1,
    const float* __restrict__ fW2, const float* __restrict__ fb2,
    const float* __restrict__ fW3, const float* __restrict__ fb3,
    float* __restrict__ wout)
{
    // activations stored transposed: [dim][token]. The 8-token vector of any
    // dim is one contiguous 32B row -> broadcast float4 x2 LDS read.
    __shared__ __align__(16) float va[VD_][TPB_];      //  9.2 KB
    __shared__ __align__(16) float ha[VD2_][TPB_];     // 18.4 KB
    __shared__ __align__(16) float comb17[NH1_][TPB_]; //  0.5 KB
    __shared__ __align__(16) float h2a[FFN_][TPB_];    // 16.4 KB
    __shared__ __align__(16) float h3a[FFNH_][TPB_];   //  8.2 KB

    const int tid  = threadIdx.x;
    const int blk  = blockIdx.x;
    const int tok0 = blk * TPB_;
    const int wid  = tid >> 6;   // wave id 0..3
    const int cthr = tid & 63;   // lane within wave
    const int t0   = wid * 2;    // token pair owned by this wave (phase 2 only)

    // ---- phase 0: embedding gather + LayerNorm(288); 32 threads/token ----
    {
        const int tt = tid >> 5;      // 0..7
        const int l  = tid & 31;
        const int id = ids[tok0 + tt];
        float x[9];
        float s = 0.f, sq = 0.f;
        #pragma unroll
        for (int r = 0; r < 9; ++r) {
            float xv = embW[id * VD_ + l + 32 * r];
            x[r] = xv; s += xv; sq += xv * xv;
        }
        #pragma unroll
        for (int m = 16; m >= 1; m >>= 1) {
            s  += __shfl_xor(s,  m, 64);
            sq += __shfl_xor(sq, m, 64);
        }
        float mu   = s * (1.f / VD_);
        float var  = sq * (1.f / VD_) - mu * mu;
        float rstd = rsqrtf(var + LN_EPS_);
        #pragma unroll
        for (int r = 0; r < 9; ++r) {
            int i = l + 32 * r;
            va[i][tt] = (x[r] - mu) * rstd * lnvw[i] + lnvb[i];
        }
    }
    __syncthreads();

    // ---- phase 1: ha = gelu(va @ pW1 + pb1)  [288 -> 576] ----
    // column-split across the WHOLE block: thread owns cols {tid, tid+256,
    // (tid<64: tid+512)} for ALL 8 tokens. Each pW1 element is loaded once
    // per block (was once per wave = 4x traffic).
    {
        float a0[TPB_], a1[TPB_], a2[TPB_];
        #pragma unroll
        for (int j = 0; j < TPB_; ++j) { a0[j] = 0.f; a1[j] = 0.f; a2[j] = 0.f; }
        const bool has3 = (tid < 64);   // wave-uniform
        #pragma unroll 2
        for (int k = 0; k < VD_; ++k) {
            const float4 vlo = *(const float4*)&va[k][0];
            const float4 vhi = *(const float4*)&va[k][4];
            const float* wrow = &pW1[k * VD2_];
            fma8(a0, wrow[tid],       vlo, vhi);
            fma8(a1, wrow[tid + 256], vlo, vhi);
            if (has3) fma8(a2, wrow[tid + 512], vlo, vhi);
        }
        store8_gelu(&ha[tid][0],       a0, pb1[tid]);
        store8_gelu(&ha[tid + 256][0], a1, pb1[tid + 256]);
        if (has3) store8_gelu(&ha[tid + 512][0], a2, pb1[tid + 512]);
    }
    __syncthreads();

    // ---- phase 2: valence = tanh(ha @ pW2 + pb2) [576 -> 16] + occ ----
    {
        const int col = cthr & 15;
        const int ks  = cthr >> 4;      // 4-way K split (144 each)
        float2 acc = make_float2(0.f, 0.f);
        for (int k = ks * 144; k < ks * 144 + 144; ++k) {
            float2 v = *(const float2*)&ha[k][t0];
            float w = pW2[k * H_ + col];
            acc.x += w * v.x; acc.y += w * v.y;
        }
        acc.x += __shfl_xor(acc.x, 16, 64); acc.y += __shfl_xor(acc.y, 16, 64);
        acc.x += __shfl_xor(acc.x, 32, 64); acc.y += __shfl_xor(acc.y, 32, 64);
        if (cthr < 16) {
            float b = pb2[col];
            float2 o = make_float2(tanhf(acc.x + b), tanhf(acc.y + b));
            *(float2*)&comb17[1 + col][t0] = o;
        }
        if (cthr == 16) {
            #pragma unroll
            for (int j = 0; j < 2; ++j) {
                int t = t0 + j;
                int id = ids[tok0 + t];
                float c = (float)counts[id];
                if (c < 1.f) c = 1.f;
                comb17[0][t] = log1pf(c);
            }
        }
    }
    __syncthreads();

    // ---- phase 3: LayerNorm(17), one thread per token ----
    if (tid < TPB_) {
        float vals[NH1_];
        float s = 0.f;
        #pragma unroll
        for (int i = 0; i < NH1_; ++i) { vals[i] = comb17[i][tid]; s += vals[i]; }
        float mu = s / NH1_;
        float vq = 0.f;
        #pragma unroll
        for (int i = 0; i < NH1_; ++i) { float d = vals[i] - mu; vq += d * d; }
        float r = rsqrtf(vq / NH1_ + LN_EPS_);
        #pragma unroll
        for (int i = 0; i < NH1_; ++i)
            comb17[i][tid] = (vals[i] - mu) * r * lncw[i] + lncb[i];
    }
    __syncthreads();

    // ---- phase 4: h2 = gelu(comb @ fW1 + fb1) [17 -> 512] ----
    // column-split: thread owns cols {tid, tid+256} for all 8 tokens.
    {
        float a0[TPB_], a1[TPB_];
        #pragma unroll
        for (int j = 0; j < TPB_; ++j) { a0[j] = 0.f; a1[j] = 0.f; }
        #pragma unroll
        for (int k = 0; k < NH1_; ++k) {
            const float4 vlo = *(const float4*)&comb17[k][0];
            const float4 vhi = *(const float4*)&comb17[k][4];
            const float* wrow = &fW1[k * FFN_];
            fma8(a0, wrow[tid],       vlo, vhi);
            fma8(a1, wrow[tid + 256], vlo, vhi);
        }
        store8_gelu(&h2a[tid][0],       a0, fb1[tid]);
        store8_gelu(&h2a[tid + 256][0], a1, fb1[tid + 256]);
    }
    __syncthreads();

    // ---- phase 5: h3 = gelu(h2 @ fW2 + fb2) [512 -> 256] ----
    // column-split: thread owns col tid for all 8 tokens.
    {
        float a0[TPB_];
        #pragma unroll
        for (int j = 0; j < TPB_; ++j) a0[j] = 0.f;
        #pragma unroll 4
        for (int k = 0; k < FFN_; ++k) {
            const float4 vlo = *(const float4*)&h2a[k][0];
            const float4 vhi = *(const float4*)&h2a[k][4];
            fma8(a0, fW2[k * FFNH_ + tid], vlo, vhi);
        }
        store8_gelu(&h3a[tid][0], a0, fb2[tid]);
    }
    __syncthreads();

    // ---- phase 6: mod = tanh(h3 . fW3 + fb3); 32 threads/token ----
    {
        const int tt = tid >> 5;
        const int l  = tid & 31;
        float acc = 0.f;
        #pragma unroll
        for (int r = 0; r < FFNH_ / 32; ++r) {
            int k = l + 32 * r;
            acc += h3a[k][tt] * fW3[k];
        }
        #pragma unroll
        for (int m = 16; m >= 1; m >>= 1) acc += __shfl_xor(acc, m, 64);
        if (l == 0) {
            float mod = tanhf(acc + fb3[0]);
            wout[tok0 + tt] = 1.0f + EPSILON_ * mod;
        }
    }
}

__global__ __launch_bounds__(256) void scale_kernel(
    const float4* __restrict__ in, const float* __restrict__ w,
    float4* __restrict__ out, long total4)
{
    long i = (long)blockIdx.x * blockDim.x + threadIdx.x;
    const long stride = (long)gridDim.x * blockDim.x;
    for (; i < total4; i += stride) {
        long row = i >> 9;                 // / (S/4=512)  -> flat row in [B*H*S)
        int b = (int)(row >> 15);          // / (H*S = 32768)
        int s = (int)(row & (S_ - 1));
        float ww = w[b * S_ + s];
        float4 x = in[i];
        x.x *= ww; x.y *= ww; x.z *= ww; x.w *= ww;
        out[i] = x;
    }
}

extern "C" void kernel_launch(void* const* d_in, const int* in_sizes, int n_in,
                              void* d_out, int out_size, void* d_ws, size_t ws_size,
                              hipStream_t stream) {
    const float* scores = (const float*)d_in[0];
    const int*   ids    = (const int*)  d_in[1];
    const float* embW   = (const float*)d_in[2];
    const float* lnvw   = (const float*)d_in[3];
    const float* lnvb   = (const float*)d_in[4];
    const float* pW1    = (const float*)d_in[5];
    const float* pb1    = (const float*)d_in[6];
    const float* pW2    = (const float*)d_in[7];
    const float* pb2    = (const float*)d_in[8];
    const float* lncw   = (const float*)d_in[9];
    const float* lncb   = (const float*)d_in[10];
    const float* fW1    = (const float*)d_in[11];
    const float* fb1    = (const float*)d_in[12];
    const float* fW2    = (const float*)d_in[13];
    const float* fb2    = (const float*)d_in[14];
    const float* fW3    = (const float*)d_in[15];
    const float* fb3    = (const float*)d_in[16];

    int*   counts = (int*)d_ws;
    float* wout   = (float*)((char*)d_ws + CTX_ * sizeof(int));

    zero_counts_kernel<<<(CTX_ + 255) / 256, 256, 0, stream>>>(counts);
    count_tokens_kernel<<<(B_ * S_ + 255) / 256, 256, 0, stream>>>(ids, counts);
    token_mlp_kernel<<<NBLK_, 256, 0, stream>>>(
        ids, counts, embW, lnvw, lnvb, pW1, pb1, pW2, pb2,
        lncw, lncb, fW1, fb1, fW2, fb2, fW3, fb3, wout);

    long total4 = (long)B_ * H_ * S_ * S_ / 4;   // 33,554,432 float4s
    scale_kernel<<<2048, 256, 0, stream>>>(
        (const float4*)scores, wout, (float4*)d_out, total4);
}